// Round 4
// baseline (230.291 us; speedup 1.0000x reference)
//
#include <hip/hip_runtime.h>
#include <hip/hip_bf16.h>
#include <stdint.h>

#define N_ROWS 16384

typedef __bf16 bf16x8 __attribute__((ext_vector_type(8)));
typedef float f32x4 __attribute__((ext_vector_type(4)));

#define AS1 __attribute__((address_space(1)))
#define AS3 __attribute__((address_space(3)))

// ---------------- ws layout (bytes) ----------------
// WcP : packed/bank-swizzled (W_token@W_qkv) bf16 image        589824
// bc  : f32 [384]                                                1536
// qb  : bf16 [16384][128] (q * -log2e)                        4194304
// kb  : bf16 [16384][128] (attn XOR-swizzled)                 4194304
// wv  : f32 [16384]                                             65536
// part: f32 [16][16384]                                       1048576
#define OFF_WCP  0u
#define OFF_BC   589824u
#define OFF_QB   591360u
#define OFF_KB   4785664u
#define OFF_WV   8979968u
#define OFF_PART 9045504u

// ---- kernel 0: Wc = W_token @ W_qkv -> bf16 packed image for DMA staging;
// per K-chunk kbi (64 k), rows n (384) stored as 2-row super-rows with 3-bit
// XOR chunk swizzle: elem idx = kbi*24576 + (n>>1)*128 + ((n&1)*8 + (j^((n>>1)&7)))*8 + k7
__global__ void prep(const float* __restrict__ Wt, const float* __restrict__ Wq,
                     const float* __restrict__ bt, const float* __restrict__ bq,
                     __bf16* __restrict__ WcP, float* __restrict__ bc) {
    int u = blockIdx.x * 256 + threadIdx.x;          // [0, 768*96)
    if (u < 768 * 96) {
        int k = u / 96, n4 = u % 96;
        float s[4] = {0, 0, 0, 0};
        const float* wtp = Wt + k * 128;
        const float* wqp = Wq + n4 * 4;
#pragma unroll 8
        for (int d = 0; d < 128; d++) {
            float a = wtp[d];
            float4 b = *(const float4*)(wqp + d * 384);
            s[0] += a * b.x; s[1] += a * b.y; s[2] += a * b.z; s[3] += a * b.w;
        }
        int kbi = k >> 6, j = (k >> 3) & 7, k7 = k & 7;
#pragma unroll
        for (int jj = 0; jj < 4; jj++) {
            int n = n4 * 4 + jj;
            int sr = n >> 1, b = n & 1;
            WcP[kbi * 24576 + sr * 128 + (b * 8 + (j ^ (sr & 7))) * 8 + k7] = (__bf16)s[jj];
        }
    }
    if (u < 384) {
        float s = bq[u];
        for (int d = 0; d < 128; d++) s += bt[d] * Wq[d * 384 + u];
        bc[u] = s;
    }
}

// ---- kernel 1: qkv = bf16(x) @ Wc + bc. BM=32, BN=384(full), BK=64.
// A (fp32) and B (bf16, pre-packed) staged via global_load_lds; 48 MFMA/wave/barrier.
__launch_bounds__(128)
__global__ void gemm_qkv(const float* __restrict__ x, const __bf16* __restrict__ WcP,
                         const float* __restrict__ bc, const float* __restrict__ W_fc,
                         __bf16* __restrict__ qb, __bf16* __restrict__ kb,
                         float* __restrict__ wv) {
    __shared__ float  Asm_[32 * 64];    // 8 KB, 16B-chunk XOR-swizzled fp32
    __shared__ __bf16 Bsm[384 * 64];    // 48 KB, packed image (matches WcP)
    const int tid = threadIdx.x, wave = tid >> 6, lane = tid & 63;
    const int n16 = lane & 15, q = lane >> 4;
    const int row0 = blockIdx.x * 32;

    // A staging src (per-lane, swizzle baked in). instr ii: rows wave*16+ii*4+(lane>>4)
    const char* asrc[4];
#pragma unroll
    for (int ii = 0; ii < 4; ii++) {
        int r = wave * 16 + ii * 4 + (lane >> 4);
        int cp = lane & 15;
        int c = 2 * ((cp >> 1) ^ (r & 7)) + ((cp & 1) ^ ((r >> 3) & 1));
        asrc[ii] = (const char*)(x + (size_t)(row0 + r) * 768 + c * 4);
    }
    const char* bsrc = (const char*)WcP + (size_t)wave * 24576 + lane * 16;

    f32x4 acc[24];
#pragma unroll
    for (int t = 0; t < 24; t++) acc[t] = (f32x4){0, 0, 0, 0};

    const int rA = wave * 16 + n16;
    const int sa = rA & 7, hb = (rA >> 3) & 1;
    const int bbase = (n16 >> 1) * 256 + (n16 & 1) * 128;   // B byte base (pre-XOR part)
    const int sb = (n16 >> 1) & 7;

    for (int kbi = 0; kbi < 12; kbi++) {
#pragma unroll
        for (int ii = 0; ii < 4; ii++)
            __builtin_amdgcn_global_load_lds((const AS1 void*)(asrc[ii] + kbi * 256),
                (AS3 void*)((char*)Asm_ + (wave * 4 + ii) * 1024 + lane * 16), 16, 0, 0);
#pragma unroll
        for (int ii = 0; ii < 24; ii++)
            __builtin_amdgcn_global_load_lds((const AS1 void*)(bsrc + (size_t)kbi * 49152 + ii * 1024),
                (AS3 void*)((char*)Bsm + (wave * 24 + ii) * 1024 + lane * 16), 16, 0, 0);
        __syncthreads();
#pragma unroll
        for (int ksub = 0; ksub < 2; ksub++) {
            const int P = ksub * 4 + q;
            const float* ap = Asm_ + rA * 64;
            f32x4 f0 = *(const f32x4*)(ap + (2 * (P ^ sa) + hb) * 4);
            f32x4 f1 = *(const f32x4*)(ap + (2 * (P ^ sa) + (1 ^ hb)) * 4);
            bf16x8 af;
            af[0] = (__bf16)f0[0]; af[1] = (__bf16)f0[1]; af[2] = (__bf16)f0[2]; af[3] = (__bf16)f0[3];
            af[4] = (__bf16)f1[0]; af[5] = (__bf16)f1[1]; af[6] = (__bf16)f1[2]; af[7] = (__bf16)f1[3];
            const char* bp = (const char*)Bsm + bbase + (P ^ sb) * 16 - (n16 & 1) * 128
                             + (n16 & 1) * 128;  // keep simple: recompute below
            (void)bp;
#pragma unroll
            for (int t = 0; t < 24; t++) {
                const char* bpt = (const char*)Bsm + (n16 >> 1) * 256
                                  + ((n16 & 1) * 8 + (P ^ sb)) * 16 + t * 2048;
                bf16x8 bf = *(const bf16x8*)bpt;
                acc[t] = __builtin_amdgcn_mfma_f32_16x16x32_bf16(af, bf, acc[t], 0, 0, 0);
            }
        }
        __syncthreads();
    }

    // epilogue: col = t*16 + n16; rows row0 + wave*16 + q*4 + r
    float wacc[4] = {0, 0, 0, 0};
#pragma unroll
    for (int t = 0; t < 24; t++) {
        int col = t * 16 + n16;
        float bcv = bc[col];
        float wf = (t >= 16) ? W_fc[col - 256] : 0.0f;
#pragma unroll
        for (int r = 0; r < 4; r++) {
            int row = row0 + wave * 16 + q * 4 + r;
            float val = acc[t][r] + bcv;
            if (t < 8) {
                qb[row * 128 + col] = (__bf16)(val * -1.44269504088896f);
            } else if (t < 16) {
                int d = col - 128;
                kb[row * 128 + (((d >> 3) ^ (row & 15)) << 3) + (d & 7)] = (__bf16)val;
            } else {
                wacc[r] += val * wf;
            }
        }
    }
#pragma unroll
    for (int r = 0; r < 4; r++) {
        float v = wacc[r];
        v += __shfl_xor(v, 1, 64);
        v += __shfl_xor(v, 2, 64);
        v += __shfl_xor(v, 4, 64);
        v += __shfl_xor(v, 8, 64);
        if (n16 == 0) wv[row0 + wave * 16 + q * 4 + r] = v;
    }
}

// ---- kernel 2: partial[sp][i] = sum_{j in slice sp} sigmoid(q_i.k_j) * wv_j ----
// 128 threads (2 waves), 64 rows/wave, 64-row K chunks (16.6 KB LDS) -> 8 blocks/CU.
__launch_bounds__(128)
__global__ void attn(const __bf16* __restrict__ qb, const __bf16* __restrict__ kb,
                     const float* __restrict__ wv, float* __restrict__ partial) {
    __shared__ __bf16 kbuf[64 * 128];
    __shared__ float wbuf[64];
    const int tid = threadIdx.x;
    const int wave = tid >> 6, lane = tid & 63;
    const int n16 = lane & 15, q = lane >> 4;
    const int row0 = blockIdx.x * 128 + wave * 64;
    const int sp = blockIdx.y;
    bf16x8 qf[4][4];
#pragma unroll
    for (int mt = 0; mt < 4; mt++)
#pragma unroll
        for (int ks = 0; ks < 4; ks++)
            qf[mt][ks] = *(const bf16x8*)(qb + (row0 + mt * 16 + n16) * 128 + ks * 32 + q * 8);
    float acc[4][4] = {{0}, {0}, {0}, {0}};
    for (int jc = 0; jc < 16; jc++) {
        const int jbase = sp * 1024 + jc * 64;
        const char* gsrc = (const char*)kb + (size_t)jbase * 256;
#pragma unroll
        for (int i = 0; i < 8; i++) {
            const int off = wave * 8192 + i * 1024;
            __builtin_amdgcn_global_load_lds(
                (const AS1 void*)(gsrc + off + lane * 16),
                (AS3 void*)((char*)kbuf + off), 16, 0, 0);
        }
        if (tid < 64) wbuf[tid] = wv[jbase + tid];
        __syncthreads();
#pragma unroll
        for (int t = 0; t < 4; t++) {
            f32x4 s[4];
#pragma unroll
            for (int mt = 0; mt < 4; mt++) s[mt] = (f32x4){0, 0, 0, 0};
#pragma unroll
            for (int ks = 0; ks < 4; ks++) {
                const int chunk = (ks * 4 + q) ^ n16;   // undo the global-side swizzle
                bf16x8 bf = *(const bf16x8*)(kbuf + (t * 16 + n16) * 128 + chunk * 8);
#pragma unroll
                for (int mt = 0; mt < 4; mt++)
                    s[mt] = __builtin_amdgcn_mfma_f32_16x16x32_bf16(qf[mt][ks], bf, s[mt], 0, 0, 0);
            }
            const float wval = wbuf[t * 16 + n16];
#pragma unroll
            for (int mt = 0; mt < 4; mt++)
#pragma unroll
                for (int r = 0; r < 4; r++)
                    // qb pre-scaled by -log2e: sigmoid(s) = rcp(1 + exp2(s'))
                    acc[mt][r] += __builtin_amdgcn_rcpf(1.0f + __builtin_amdgcn_exp2f(s[mt][r])) * wval;
        }
        __syncthreads();
    }
#pragma unroll
    for (int mt = 0; mt < 4; mt++)
#pragma unroll
        for (int r = 0; r < 4; r++) {
            float v = acc[mt][r];
            v += __shfl_xor(v, 1, 64);
            v += __shfl_xor(v, 2, 64);
            v += __shfl_xor(v, 4, 64);
            v += __shfl_xor(v, 8, 64);
            if (n16 == 0) partial[sp * N_ROWS + row0 + mt * 16 + q * 4 + r] = v;
        }
}

// ---- kernel 3: deterministic reduce over 16 slices + b_fc ----
__global__ void reduce_out(const float* __restrict__ partial, const float* __restrict__ b_fc,
                           float* __restrict__ out) {
    int i = blockIdx.x * 256 + threadIdx.x;
    float v = b_fc[0];
#pragma unroll
    for (int s = 0; s < 16; s++) v += partial[s * N_ROWS + i];
    out[i] = v;
}

extern "C" void kernel_launch(void* const* d_in, const int* in_sizes, int n_in,
                              void* d_out, int out_size, void* d_ws, size_t ws_size,
                              hipStream_t stream) {
    const float* x       = (const float*)d_in[0];
    // d_in[1] = decay_value (unused by reference)
    const float* W_token = (const float*)d_in[2];
    const float* b_token = (const float*)d_in[3];
    const float* W_qkv   = (const float*)d_in[4];
    const float* b_qkv   = (const float*)d_in[5];
    const float* W_fc    = (const float*)d_in[6];
    const float* b_fc    = (const float*)d_in[7];
    float* out = (float*)d_out;
    char* ws = (char*)d_ws;

    __bf16* WcP = (__bf16*)(ws + OFF_WCP);
    float*  bc  = (float*)(ws + OFF_BC);
    __bf16* qb  = (__bf16*)(ws + OFF_QB);
    __bf16* kb  = (__bf16*)(ws + OFF_KB);
    float*  wv  = (float*)(ws + OFF_WV);
    float*  part = (float*)(ws + OFF_PART);

    prep<<<288, 256, 0, stream>>>(W_token, W_qkv, b_token, b_qkv, WcP, bc);
    gemm_qkv<<<512, 128, 0, stream>>>(x, WcP, bc, W_fc, qb, kb, wv);
    attn<<<dim3(128, 16), 128, 0, stream>>>(qb, kb, wv, part);
    reduce_out<<<64, 256, 0, stream>>>(part, b_fc, out);
}